// Round 15
// baseline (171.660 us; speedup 1.0000x reference)
//
#include <hip/hip_runtime.h>

#define IN_F 256
#define OUT_F 128
#define ALPHA 0.2f
#define EPS 9e-15f
#define NBUCK_MAX 512      // ceil(n/128) = 391 for n = 50000
#define CHUNK 8192
#define LDST 40            // padded LDS row stride in ushorts (32 data + 8 pad)
#define GEMM_BLOCKS 391    // (50000+127)/128
#define HIST_BLOCKS 1024

typedef __attribute__((ext_vector_type(8))) short bf16x8;
typedef __attribute__((ext_vector_type(4))) float f32x4;

__device__ __forceinline__ unsigned bf16rnd(float f) {
    unsigned b = __float_as_uint(f);
    return b + 0x7FFFu + ((b >> 16) & 1u);   // take >>16 for the bf16 payload
}

// ---------------- K0: zero bcnt (block 0) + W -> Wt bf16 [col][k] (blocks 1..128) ----------------
__global__ __launch_bounds__(256) void k_init(const float* __restrict__ W,
                                              unsigned short* __restrict__ Wt,
                                              int* __restrict__ bcnt) {
    int t = threadIdx.x;
    if (blockIdx.x == 0) {
        if (t < NBUCK_MAX) bcnt[t] = 0;
        if (t + 256 < NBUCK_MAX) bcnt[t + 256] = 0;
        return;
    }
    int idx = (blockIdx.x - 1) * 256 + t;
    int k = idx >> 7, col = idx & 127;
    Wt[col * IN_F + k] = (unsigned short)(bf16rnd(W[idx]) >> 16);
}

// ---------------- K1 (fat): blocks [0,GEMM_BLOCKS) = GEMM; rest = edge histogram ----------------
__global__ __launch_bounds__(256) void k_gemm_hist(const float* __restrict__ input,
                                                   const unsigned short* __restrict__ Wt,
                                                   const float* __restrict__ a,
                                                   unsigned short* __restrict__ hb,
                                                   float* __restrict__ hs,
                                                   float* __restrict__ hd,
                                                   const int* __restrict__ ei,
                                                   int* __restrict__ bcnt,
                                                   int nE, int n) {
    __shared__ unsigned short Ah[128 * LDST];
    __shared__ unsigned short Bt[128 * LDST];
    __shared__ int bh[NBUCK_MAX];

    const int t = threadIdx.x;

    if (blockIdx.x >= GEMM_BLOCKS) {
        // ---------------- histogram part ----------------
        for (int i = t; i < NBUCK_MAX; i += 256) bh[i] = 0;
        __syncthreads();
        int stride = HIST_BLOCKS * 256;
        for (int e = (blockIdx.x - GEMM_BLOCKS) * 256 + t; e < nE; e += stride) {
            int s = ei[e];
            s = min(max(s, 0), n - 1);
            atomicAdd(&bh[s >> 7], 1);
        }
        __syncthreads();
        int nbuck = (n + 127) >> 7;
        for (int i = t; i < nbuck; i += 256)
            if (bh[i]) atomicAdd(&bcnt[i], bh[i]);
        return;
    }

    // ---------------- GEMM part ----------------
    const int lane = t & 63;
    const int wave = t >> 6;
    const int l15 = lane & 15;
    const int l4 = lane >> 4;
    const int row0 = blockIdx.x * 128;

    f32x4 acc[2][8];
#pragma unroll
    for (int rt = 0; rt < 2; ++rt)
#pragma unroll
        for (int ct = 0; ct < 8; ++ct) acc[rt][ct] = (f32x4)(0.f);

    for (int ks = 0; ks < 8; ++ks) {
#pragma unroll
        for (int c = t; c < 512; c += 256) {
            int row = c >> 2, kg = c & 3;
            int grow = row0 + row;
            float4 v0 = make_float4(0.f, 0.f, 0.f, 0.f);
            float4 v1 = v0;
            if (grow < n) {
                const float4* src = (const float4*)&input[(size_t)grow * IN_F + ks * 32 + kg * 8];
                v0 = src[0];
                v1 = src[1];
            }
            float xs[8] = {v0.x, v0.y, v0.z, v0.w, v1.x, v1.y, v1.z, v1.w};
            unsigned h[8];
#pragma unroll
            for (int j = 0; j < 8; ++j) h[j] = bf16rnd(xs[j]) >> 16;
            uint4 ph = make_uint4(h[0] | (h[1] << 16), h[2] | (h[3] << 16),
                                  h[4] | (h[5] << 16), h[6] | (h[7] << 16));
            *(uint4*)&Ah[row * LDST + kg * 8] = ph;
        }
#pragma unroll
        for (int c = t; c < 512; c += 256) {
            int col = c >> 2, kg = c & 3;
            uint4 v = *(const uint4*)&Wt[col * IN_F + ks * 32 + kg * 8];
            *(uint4*)&Bt[col * LDST + kg * 8] = v;
        }
        __syncthreads();

        bf16x8 a_h[2];
#pragma unroll
        for (int rt = 0; rt < 2; ++rt) {
            int base = (wave * 32 + rt * 16 + l15) * LDST + l4 * 8;
            a_h[rt] = *(bf16x8*)&Ah[base];
        }
#pragma unroll
        for (int ct = 0; ct < 8; ++ct) {
            bf16x8 b = *(bf16x8*)&Bt[(ct * 16 + l15) * LDST + l4 * 8];
            acc[0][ct] = __builtin_amdgcn_mfma_f32_16x16x32_bf16(a_h[0], b, acc[0][ct], 0, 0, 0);
            acc[1][ct] = __builtin_amdgcn_mfma_f32_16x16x32_bf16(a_h[1], b, acc[1][ct], 0, 0, 0);
        }
        __syncthreads();
    }

    float as8[8], ad8[8];
#pragma unroll
    for (int ct = 0; ct < 8; ++ct) {
        as8[ct] = a[ct * 16 + l15];
        ad8[ct] = a[OUT_F + ct * 16 + l15];
    }
#pragma unroll
    for (int rt = 0; rt < 2; ++rt) {
#pragma unroll
        for (int r = 0; r < 4; ++r) {
            int grow = row0 + wave * 32 + rt * 16 + l4 * 4 + r;
            float ps = 0.f, pd = 0.f;
#pragma unroll
            for (int ct = 0; ct < 8; ++ct) {
                float v = acc[rt][ct][r];
                ps = fmaf(v, as8[ct], ps);
                pd = fmaf(v, ad8[ct], pd);
            }
#pragma unroll
            for (int o = 8; o; o >>= 1) {
                ps += __shfl_xor(ps, o);
                pd += __shfl_xor(pd, o);
            }
            if (grow < n) {
#pragma unroll
                for (int ct = 0; ct < 8; ++ct)
                    hb[(size_t)grow * OUT_F + ct * 16 + l15] =
                        (unsigned short)(bf16rnd(acc[rt][ct][r]) >> 16);
                if (l15 == 0) { hs[grow] = ps; hd[grow] = pd; }
            }
        }
    }
}

// ---------------- bucket scan: bcnt -> boffB (exclusive), init bcursor ----------------
__global__ __launch_bounds__(256) void k_scanB(const int* __restrict__ bcnt,
                                               int* __restrict__ boffB,
                                               int* __restrict__ bcursor,
                                               int nbuck) {
    __shared__ int sA[NBUCK_MAX], sB[NBUCK_MAX];
    int t = threadIdx.x;
    for (int i = t; i < NBUCK_MAX; i += 256) sA[i] = (i < nbuck) ? bcnt[i] : 0;
    __syncthreads();
    int *src = sA, *dst = sB;
    for (int ofs = 1; ofs < NBUCK_MAX; ofs <<= 1) {
        for (int i = t; i < NBUCK_MAX; i += 256)
            dst[i] = src[i] + (i >= ofs ? src[i - ofs] : 0);
        __syncthreads();
        int* tmp = src; src = dst; dst = tmp;
    }
    for (int i = t; i < nbuck; i += 256) {
        int ex = i ? src[i - 1] : 0;
        boffB[i] = ex;
        bcursor[i] = ex;
    }
}

// ---------------- K3: FUSED per-edge score + binned scatter (register-staged) ----------------
// 1024 threads, 8 edges/thread, CHUNK 8192.
// rk word: [0:13)=local rank, [13:22)=bucket, [22:29)=s&127
__global__ __launch_bounds__(1024) void k_edgebin(const int* __restrict__ ei,
                                                  const float* __restrict__ ew,
                                                  const float* __restrict__ er,
                                                  const float* __restrict__ hs,
                                                  const float* __restrict__ hd,
                                                  const float* __restrict__ Wr,
                                                  const float* __restrict__ a,
                                                  int* __restrict__ bcursor,
                                                  int2* __restrict__ binned,
                                                  int nE, int n) {
    __shared__ float war[8];
    __shared__ int bcl[NBUCK_MAX];
    __shared__ int gbase[NBUCK_MAX];
    const int t = threadIdx.x;
    const int base = blockIdx.x * CHUNK;
    if (t < NBUCK_MAX) bcl[t] = 0;
    if (t < 256) {
        int rr = t >> 5;
        int l5 = t & 31;
        float p = 0.f;
#pragma unroll
        for (int k = 0; k < 4; ++k)
            p = fmaf(Wr[rr * OUT_F + l5 * 4 + k], a[2 * OUT_F + l5 * 4 + k], p);
#pragma unroll
        for (int o = 16; o; o >>= 1) p += __shfl_xor(p, o, 32);
        if (l5 == 0) war[rr] = p;
    }
    __syncthreads();

    const float aw = a[3 * OUT_F];
    unsigned rk[8];
    float eev[8];
    unsigned short dv[8];
#pragma unroll
    for (int r = 0; r < 8; ++r) {
        int i = r * 1024 + t;
        int e = base + i;
        rk[r] = 0xFFFFFFFFu;
        if (e < nE) {
            int s = ei[e], d = ei[nE + e];
            s = min(max(s, 0), n - 1);
            d = min(max(d, 0), n - 1);
            float4 r0 = *(const float4*)&er[(size_t)e * 8];
            float4 r1 = *(const float4*)&er[(size_t)e * 8 + 4];
            float sc = hs[s] + hd[d]
                     + r0.x * war[0] + r0.y * war[1] + r0.z * war[2] + r0.w * war[3]
                     + r1.x * war[4] + r1.y * war[5] + r1.z * war[6] + r1.w * war[7]
                     + aw * ew[e];
            float lr = sc > 0.f ? sc : ALPHA * sc;
            int b = s >> 7;
            int rank = atomicAdd(&bcl[b], 1);
            rk[r] = (unsigned)rank | ((unsigned)b << 13) | ((unsigned)(s & 127) << 22);
            eev[r] = expf(-lr);
            dv[r] = (unsigned short)d;
        }
    }
    __syncthreads();
    if (t < NBUCK_MAX) {
        int c = bcl[t];
        gbase[t] = c ? atomicAdd(&bcursor[t], c) : 0;
    }
    __syncthreads();
#pragma unroll
    for (int r = 0; r < 8; ++r) {
        if (rk[r] != 0xFFFFFFFFu) {
            int rank = rk[r] & 8191;
            int b = (rk[r] >> 13) & 0x1FF;
            int sl = (rk[r] >> 22) & 127;
            int2 pr;
            pr.x = (int)dv[r] | (sl << 16);
            pr.y = __float_as_int(eev[r]);
            binned[gbase[b] + rank] = pr;
        }
    }
}

// ---------------- K5: per-bucket node count + scan + scatter to CSR ----------------
__global__ __launch_bounds__(1024) void k_sub(const int2* __restrict__ binned,
                                              const int* __restrict__ bcnt,
                                              const int* __restrict__ boffB,
                                              int* __restrict__ offs,
                                              int2* __restrict__ pairs, int n, int nE) {
    __shared__ int cnt_l[128];
    __shared__ int sA[128], sB[128];
    __shared__ int cur[128];
    int b = blockIdx.x;
    int t = threadIdx.x;
    int node0 = b << 7;
    if (t < 128) cnt_l[t] = 0;
    __syncthreads();
    int beg = boffB[b], c = bcnt[b];
    const long long* bp = (const long long*)binned;
    for (int i = t; i < c; i += 1024) {
        long long v = __builtin_nontemporal_load(bp + beg + i);
        int sl = ((int)(v & 0xFFFFFFFF) >> 16) & 127;
        atomicAdd(&cnt_l[sl], 1);
    }
    __syncthreads();
    if (t < 128) sA[t] = cnt_l[t];
    __syncthreads();
    int *src = sA, *dst = sB;
    for (int ofs = 1; ofs < 128; ofs <<= 1) {
        if (t < 128) dst[t] = src[t] + (t >= ofs ? src[t - ofs] : 0);
        __syncthreads();
        int* tmp = src; src = dst; dst = tmp;
    }
    if (t < 128) {
        int ex = t ? src[t - 1] : 0;
        int node = node0 + t;
        if (node < n) offs[node] = beg + ex;
        cur[t] = ex;
    }
    if (t == 0 && b == 0) offs[n] = nE;
    __syncthreads();
    for (int i = t; i < c; i += 1024) {
        long long v = __builtin_nontemporal_load(bp + beg + i);
        int px = (int)(v & 0xFFFFFFFF);
        int py = (int)(v >> 32);
        int sl = (px >> 16) & 127;
        int pos = beg + atomicAdd(&cur[sl], 1);
        int2 o;
        o.x = px & 0xFFFF;
        o.y = py;
        pairs[pos] = o;
    }
}

// ---------------- K6: per-node accumulation + finalize (elu), bf16 h gather ----------------
// Nontemporal pairs loads / out stores keep L2 for hb rows.
__global__ __launch_bounds__(256) void k_acc(const int2* __restrict__ pairs,
                                             const int* __restrict__ offs,
                                             const unsigned* __restrict__ hb,
                                             float* __restrict__ out, int n) {
    int wid = threadIdx.x >> 6, lane = threadIdx.x & 63;
    int node = blockIdx.x * 4 + wid;
    if (node >= n) return;
    int beg = offs[node], end = offs[node + 1];
    float ax = 0.f, ay = 0.f, rowsum = 0.f;
    const long long* pp = (const long long*)pairs;
    int idx = beg;
    for (; idx + 16 <= end; idx += 16) {
        long long p[16];
        unsigned u[16];
#pragma unroll
        for (int j = 0; j < 16; ++j) p[j] = __builtin_nontemporal_load(pp + idx + j);
#pragma unroll
        for (int j = 0; j < 16; ++j)
            u[j] = hb[(size_t)(unsigned)(p[j] & 0xFFFFFFFF) * 64 + lane];
#pragma unroll
        for (int j = 0; j < 16; ++j) {
            float ee = __int_as_float((int)(p[j] >> 32));
            float hx = __uint_as_float(u[j] << 16);
            float hy = __uint_as_float(u[j] & 0xFFFF0000u);
            ax = fmaf(ee, hx, ax);
            ay = fmaf(ee, hy, ay);
            rowsum += ee;
        }
    }
    for (; idx + 8 <= end; idx += 8) {
        long long p[8];
        unsigned u[8];
#pragma unroll
        for (int j = 0; j < 8; ++j) p[j] = __builtin_nontemporal_load(pp + idx + j);
#pragma unroll
        for (int j = 0; j < 8; ++j)
            u[j] = hb[(size_t)(unsigned)(p[j] & 0xFFFFFFFF) * 64 + lane];
#pragma unroll
        for (int j = 0; j < 8; ++j) {
            float ee = __int_as_float((int)(p[j] >> 32));
            float hx = __uint_as_float(u[j] << 16);
            float hy = __uint_as_float(u[j] & 0xFFFF0000u);
            ax = fmaf(ee, hx, ax);
            ay = fmaf(ee, hy, ay);
            rowsum += ee;
        }
    }
    for (; idx < end; ++idx) {
        long long pv = __builtin_nontemporal_load(pp + idx);
        float ee = __int_as_float((int)(pv >> 32));
        unsigned u = hb[(size_t)(unsigned)(pv & 0xFFFFFFFF) * 64 + lane];
        float hx = __uint_as_float(u << 16);
        float hy = __uint_as_float(u & 0xFFFF0000u);
        ax = fmaf(ee, hx, ax);
        ay = fmaf(ee, hy, ay);
        rowsum += ee;
    }
    float inv = 1.f / (rowsum + EPS);
    float x = ax * inv, y = ay * inv;
    x = x > 0.f ? x : (expf(x) - 1.f);
    y = y > 0.f ? y : (expf(y) - 1.f);
    union { float2 f; long long l; } uo;
    uo.f = make_float2(x, y);
    __builtin_nontemporal_store(uo.l, (long long*)&out[(size_t)node * OUT_F + lane * 2]);
}

static inline size_t align_up(size_t v, size_t al) { return (v + al - 1) & ~(al - 1); }

extern "C" void kernel_launch(void* const* d_in, const int* in_sizes, int n_in,
                              void* d_out, int out_size, void* d_ws, size_t ws_size,
                              hipStream_t stream) {
    const float* input = (const float*)d_in[0];
    const int*   ei    = (const int*)d_in[1];
    const float* ew    = (const float*)d_in[2];
    const float* er    = (const float*)d_in[3];
    const float* W     = (const float*)d_in[4];
    const float* Wr    = (const float*)d_in[5];
    const float* a     = (const float*)d_in[6];
    float* out = (float*)d_out;

    const int n  = in_sizes[0] / IN_F;   // 50000
    const int nE = in_sizes[2];          // 1600000
    const int nbuck = (n + 127) >> 7;    // 391

    char* p = (char*)d_ws;
    size_t o = 0;
    unsigned short* hb = (unsigned short*)(p + o); o = align_up(o + (size_t)n * OUT_F * 2, 256);
    unsigned short* Wt = (unsigned short*)(p + o); o = align_up(o + (size_t)IN_F * OUT_F * 2, 256);
    float* hs      = (float*)(p + o); o = align_up(o + (size_t)n * 4, 256);
    float* hd      = (float*)(p + o); o = align_up(o + (size_t)n * 4, 256);
    int*   offs    = (int*)(p + o);   o = align_up(o + (size_t)(n + 1) * 4, 256);
    int2*  pairs   = (int2*)(p + o);  o = align_up(o + (size_t)nE * 8, 256);
    int2*  binned  = (int2*)(p + o);  o = align_up(o + (size_t)nE * 8, 256);
    int*   bcnt    = (int*)(p + o);   o = align_up(o + NBUCK_MAX * 4, 256);
    int*   boffB   = (int*)(p + o);   o = align_up(o + NBUCK_MAX * 4, 256);
    int*   bcursor = (int*)(p + o);   o = align_up(o + NBUCK_MAX * 4, 256);
    (void)ws_size; (void)n_in; (void)out_size;

    k_init<<<129, 256, 0, stream>>>(W, Wt, bcnt);
    k_gemm_hist<<<GEMM_BLOCKS + HIST_BLOCKS, 256, 0, stream>>>(input, Wt, a, hb, hs, hd,
                                                               ei, bcnt, nE, n);
    k_scanB<<<1, 256, 0, stream>>>(bcnt, boffB, bcursor, nbuck);
    int nchunk = (nE + CHUNK - 1) / CHUNK;
    k_edgebin<<<nchunk, 1024, 0, stream>>>(ei, ew, er, hs, hd, Wr, a,
                                           bcursor, binned, nE, n);
    k_sub<<<nbuck, 1024, 0, stream>>>(binned, bcnt, boffB, offs, pairs, n, nE);
    k_acc<<<(n + 3) / 4, 256, 0, stream>>>(pairs, offs, (const unsigned*)hb, out, n);
}

// Round 16
// 141.254 us; speedup vs baseline: 1.2153x; 1.2153x over previous
//
#include <hip/hip_runtime.h>

#define IN_F 256
#define OUT_F 128
#define ALPHA 0.2f
#define EPS 9e-15f
#define NBUCK_MAX 512      // ceil(n/128) = 391 for n = 50000
#define CHUNK 8192
#define LDST 40            // padded LDS row stride in ushorts (32 data + 8 pad)
#define GEMM_BLOCKS 391    // (50000+127)/128
#define HIST_BLOCKS 1024

typedef __attribute__((ext_vector_type(8))) short bf16x8;
typedef __attribute__((ext_vector_type(4))) float f32x4;

__device__ __forceinline__ unsigned bf16rnd(float f) {
    unsigned b = __float_as_uint(f);
    return b + 0x7FFFu + ((b >> 16) & 1u);   // take >>16 for the bf16 payload
}

// ---------------- K0: zero bcnt (block 0) + W -> Wt bf16 [col][k] (blocks 1..128) ----------------
__global__ __launch_bounds__(256) void k_init(const float* __restrict__ W,
                                              unsigned short* __restrict__ Wt,
                                              int* __restrict__ bcnt) {
    int t = threadIdx.x;
    if (blockIdx.x == 0) {
        if (t < NBUCK_MAX) bcnt[t] = 0;
        if (t + 256 < NBUCK_MAX) bcnt[t + 256] = 0;
        return;
    }
    int idx = (blockIdx.x - 1) * 256 + t;
    int k = idx >> 7, col = idx & 127;
    Wt[col * IN_F + k] = (unsigned short)(bf16rnd(W[idx]) >> 16);
}

// ---------------- K1 (fat): blocks [0,GEMM_BLOCKS) = GEMM; rest = edge histogram ----------------
__global__ __launch_bounds__(256) void k_gemm_hist(const float* __restrict__ input,
                                                   const unsigned short* __restrict__ Wt,
                                                   const float* __restrict__ a,
                                                   unsigned short* __restrict__ hb,
                                                   float* __restrict__ hs,
                                                   float* __restrict__ hd,
                                                   const int* __restrict__ ei,
                                                   int* __restrict__ bcnt,
                                                   int nE, int n) {
    __shared__ unsigned short Ah[128 * LDST];
    __shared__ unsigned short Bt[128 * LDST];
    __shared__ int bh[NBUCK_MAX];

    const int t = threadIdx.x;

    if (blockIdx.x >= GEMM_BLOCKS) {
        // ---------------- histogram part ----------------
        for (int i = t; i < NBUCK_MAX; i += 256) bh[i] = 0;
        __syncthreads();
        int stride = HIST_BLOCKS * 256;
        for (int e = (blockIdx.x - GEMM_BLOCKS) * 256 + t; e < nE; e += stride) {
            int s = ei[e];
            s = min(max(s, 0), n - 1);
            atomicAdd(&bh[s >> 7], 1);
        }
        __syncthreads();
        int nbuck = (n + 127) >> 7;
        for (int i = t; i < nbuck; i += 256)
            if (bh[i]) atomicAdd(&bcnt[i], bh[i]);
        return;
    }

    // ---------------- GEMM part ----------------
    const int lane = t & 63;
    const int wave = t >> 6;
    const int l15 = lane & 15;
    const int l4 = lane >> 4;
    const int row0 = blockIdx.x * 128;

    f32x4 acc[2][8];
#pragma unroll
    for (int rt = 0; rt < 2; ++rt)
#pragma unroll
        for (int ct = 0; ct < 8; ++ct) acc[rt][ct] = (f32x4)(0.f);

    for (int ks = 0; ks < 8; ++ks) {
#pragma unroll
        for (int c = t; c < 512; c += 256) {
            int row = c >> 2, kg = c & 3;
            int grow = row0 + row;
            float4 v0 = make_float4(0.f, 0.f, 0.f, 0.f);
            float4 v1 = v0;
            if (grow < n) {
                const float4* src = (const float4*)&input[(size_t)grow * IN_F + ks * 32 + kg * 8];
                v0 = src[0];
                v1 = src[1];
            }
            float xs[8] = {v0.x, v0.y, v0.z, v0.w, v1.x, v1.y, v1.z, v1.w};
            unsigned h[8];
#pragma unroll
            for (int j = 0; j < 8; ++j) h[j] = bf16rnd(xs[j]) >> 16;
            uint4 ph = make_uint4(h[0] | (h[1] << 16), h[2] | (h[3] << 16),
                                  h[4] | (h[5] << 16), h[6] | (h[7] << 16));
            *(uint4*)&Ah[row * LDST + kg * 8] = ph;
        }
#pragma unroll
        for (int c = t; c < 512; c += 256) {
            int col = c >> 2, kg = c & 3;
            uint4 v = *(const uint4*)&Wt[col * IN_F + ks * 32 + kg * 8];
            *(uint4*)&Bt[col * LDST + kg * 8] = v;
        }
        __syncthreads();

        bf16x8 a_h[2];
#pragma unroll
        for (int rt = 0; rt < 2; ++rt) {
            int base = (wave * 32 + rt * 16 + l15) * LDST + l4 * 8;
            a_h[rt] = *(bf16x8*)&Ah[base];
        }
#pragma unroll
        for (int ct = 0; ct < 8; ++ct) {
            bf16x8 b = *(bf16x8*)&Bt[(ct * 16 + l15) * LDST + l4 * 8];
            acc[0][ct] = __builtin_amdgcn_mfma_f32_16x16x32_bf16(a_h[0], b, acc[0][ct], 0, 0, 0);
            acc[1][ct] = __builtin_amdgcn_mfma_f32_16x16x32_bf16(a_h[1], b, acc[1][ct], 0, 0, 0);
        }
        __syncthreads();
    }

    float as8[8], ad8[8];
#pragma unroll
    for (int ct = 0; ct < 8; ++ct) {
        as8[ct] = a[ct * 16 + l15];
        ad8[ct] = a[OUT_F + ct * 16 + l15];
    }
#pragma unroll
    for (int rt = 0; rt < 2; ++rt) {
#pragma unroll
        for (int r = 0; r < 4; ++r) {
            int grow = row0 + wave * 32 + rt * 16 + l4 * 4 + r;
            float ps = 0.f, pd = 0.f;
#pragma unroll
            for (int ct = 0; ct < 8; ++ct) {
                float v = acc[rt][ct][r];
                ps = fmaf(v, as8[ct], ps);
                pd = fmaf(v, ad8[ct], pd);
            }
#pragma unroll
            for (int o = 8; o; o >>= 1) {
                ps += __shfl_xor(ps, o);
                pd += __shfl_xor(pd, o);
            }
            if (grow < n) {
#pragma unroll
                for (int ct = 0; ct < 8; ++ct)
                    hb[(size_t)grow * OUT_F + ct * 16 + l15] =
                        (unsigned short)(bf16rnd(acc[rt][ct][r]) >> 16);
                if (l15 == 0) { hs[grow] = ps; hd[grow] = pd; }
            }
        }
    }
}

// ---------------- bucket scan: bcnt -> boffB (exclusive), init bcursor ----------------
__global__ __launch_bounds__(256) void k_scanB(const int* __restrict__ bcnt,
                                               int* __restrict__ boffB,
                                               int* __restrict__ bcursor,
                                               int nbuck) {
    __shared__ int sA[NBUCK_MAX], sB[NBUCK_MAX];
    int t = threadIdx.x;
    for (int i = t; i < NBUCK_MAX; i += 256) sA[i] = (i < nbuck) ? bcnt[i] : 0;
    __syncthreads();
    int *src = sA, *dst = sB;
    for (int ofs = 1; ofs < NBUCK_MAX; ofs <<= 1) {
        for (int i = t; i < NBUCK_MAX; i += 256)
            dst[i] = src[i] + (i >= ofs ? src[i - ofs] : 0);
        __syncthreads();
        int* tmp = src; src = dst; dst = tmp;
    }
    for (int i = t; i < nbuck; i += 256) {
        int ex = i ? src[i - 1] : 0;
        boffB[i] = ex;
        bcursor[i] = ex;
    }
}

// ---------------- K3: FUSED per-edge score + binned scatter (register-staged) ----------------
// 1024 threads, 8 edges/thread, CHUNK 8192.
// rk word: [0:13)=local rank, [13:22)=bucket, [22:29)=s&127
__global__ __launch_bounds__(1024) void k_edgebin(const int* __restrict__ ei,
                                                  const float* __restrict__ ew,
                                                  const float* __restrict__ er,
                                                  const float* __restrict__ hs,
                                                  const float* __restrict__ hd,
                                                  const float* __restrict__ Wr,
                                                  const float* __restrict__ a,
                                                  int* __restrict__ bcursor,
                                                  int2* __restrict__ binned,
                                                  int nE, int n) {
    __shared__ float war[8];
    __shared__ int bcl[NBUCK_MAX];
    __shared__ int gbase[NBUCK_MAX];
    const int t = threadIdx.x;
    const int base = blockIdx.x * CHUNK;
    if (t < NBUCK_MAX) bcl[t] = 0;
    if (t < 256) {
        int rr = t >> 5;
        int l5 = t & 31;
        float p = 0.f;
#pragma unroll
        for (int k = 0; k < 4; ++k)
            p = fmaf(Wr[rr * OUT_F + l5 * 4 + k], a[2 * OUT_F + l5 * 4 + k], p);
#pragma unroll
        for (int o = 16; o; o >>= 1) p += __shfl_xor(p, o, 32);
        if (l5 == 0) war[rr] = p;
    }
    __syncthreads();

    const float aw = a[3 * OUT_F];
    unsigned rk[8];
    float eev[8];
    unsigned short dv[8];
#pragma unroll
    for (int r = 0; r < 8; ++r) {
        int i = r * 1024 + t;
        int e = base + i;
        rk[r] = 0xFFFFFFFFu;
        if (e < nE) {
            int s = ei[e], d = ei[nE + e];
            s = min(max(s, 0), n - 1);
            d = min(max(d, 0), n - 1);
            float4 r0 = *(const float4*)&er[(size_t)e * 8];
            float4 r1 = *(const float4*)&er[(size_t)e * 8 + 4];
            float sc = hs[s] + hd[d]
                     + r0.x * war[0] + r0.y * war[1] + r0.z * war[2] + r0.w * war[3]
                     + r1.x * war[4] + r1.y * war[5] + r1.z * war[6] + r1.w * war[7]
                     + aw * ew[e];
            float lr = sc > 0.f ? sc : ALPHA * sc;
            int b = s >> 7;
            int rank = atomicAdd(&bcl[b], 1);
            rk[r] = (unsigned)rank | ((unsigned)b << 13) | ((unsigned)(s & 127) << 22);
            eev[r] = expf(-lr);
            dv[r] = (unsigned short)d;
        }
    }
    __syncthreads();
    if (t < NBUCK_MAX) {
        int c = bcl[t];
        gbase[t] = c ? atomicAdd(&bcursor[t], c) : 0;
    }
    __syncthreads();
#pragma unroll
    for (int r = 0; r < 8; ++r) {
        if (rk[r] != 0xFFFFFFFFu) {
            int rank = rk[r] & 8191;
            int b = (rk[r] >> 13) & 0x1FF;
            int sl = (rk[r] >> 22) & 127;
            int2 pr;
            pr.x = (int)dv[r] | (sl << 16);
            pr.y = __float_as_int(eev[r]);
            binned[gbase[b] + rank] = pr;
        }
    }
}

// ---------------- K5: per-bucket node count + scan + scatter to CSR ----------------
__global__ __launch_bounds__(1024) void k_sub(const int2* __restrict__ binned,
                                              const int* __restrict__ bcnt,
                                              const int* __restrict__ boffB,
                                              int* __restrict__ offs,
                                              int2* __restrict__ pairs, int n, int nE) {
    __shared__ int cnt_l[128];
    __shared__ int sA[128], sB[128];
    __shared__ int cur[128];
    int b = blockIdx.x;
    int t = threadIdx.x;
    int node0 = b << 7;
    if (t < 128) cnt_l[t] = 0;
    __syncthreads();
    int beg = boffB[b], c = bcnt[b];
    for (int i = t; i < c; i += 1024) {
        int sl = (binned[beg + i].x >> 16) & 127;
        atomicAdd(&cnt_l[sl], 1);
    }
    __syncthreads();
    if (t < 128) sA[t] = cnt_l[t];
    __syncthreads();
    int *src = sA, *dst = sB;
    for (int ofs = 1; ofs < 128; ofs <<= 1) {
        if (t < 128) dst[t] = src[t] + (t >= ofs ? src[t - ofs] : 0);
        __syncthreads();
        int* tmp = src; src = dst; dst = tmp;
    }
    if (t < 128) {
        int ex = t ? src[t - 1] : 0;
        int node = node0 + t;
        if (node < n) offs[node] = beg + ex;
        cur[t] = ex;
    }
    if (t == 0 && b == 0) offs[n] = nE;
    __syncthreads();
    for (int i = t; i < c; i += 1024) {
        int2 pr = binned[beg + i];
        int sl = (pr.x >> 16) & 127;
        int pos = beg + atomicAdd(&cur[sl], 1);
        int2 o;
        o.x = pr.x & 0xFFFF;
        o.y = pr.y;
        pairs[pos] = o;
    }
}

// ---------------- K6: per-node accumulation + finalize (elu), bf16 h gather ----------------
// 16-deep gather pipeline for MLP; 8-deep + scalar tail.
__global__ __launch_bounds__(256) void k_acc(const int2* __restrict__ pairs,
                                             const int* __restrict__ offs,
                                             const unsigned* __restrict__ hb,
                                             float* __restrict__ out, int n) {
    int wid = threadIdx.x >> 6, lane = threadIdx.x & 63;
    int node = blockIdx.x * 4 + wid;
    if (node >= n) return;
    int beg = offs[node], end = offs[node + 1];
    float ax = 0.f, ay = 0.f, rowsum = 0.f;
    int idx = beg;
    for (; idx + 16 <= end; idx += 16) {
        int2 p[16];
        unsigned u[16];
#pragma unroll
        for (int j = 0; j < 16; ++j) p[j] = pairs[idx + j];
#pragma unroll
        for (int j = 0; j < 16; ++j)
            u[j] = hb[(size_t)p[j].x * 64 + lane];
#pragma unroll
        for (int j = 0; j < 16; ++j) {
            float ee = __int_as_float(p[j].y);
            float hx = __uint_as_float(u[j] << 16);
            float hy = __uint_as_float(u[j] & 0xFFFF0000u);
            ax = fmaf(ee, hx, ax);
            ay = fmaf(ee, hy, ay);
            rowsum += ee;
        }
    }
    for (; idx + 8 <= end; idx += 8) {
        int2 p[8];
        unsigned u[8];
#pragma unroll
        for (int j = 0; j < 8; ++j) p[j] = pairs[idx + j];
#pragma unroll
        for (int j = 0; j < 8; ++j)
            u[j] = hb[(size_t)p[j].x * 64 + lane];
#pragma unroll
        for (int j = 0; j < 8; ++j) {
            float ee = __int_as_float(p[j].y);
            float hx = __uint_as_float(u[j] << 16);
            float hy = __uint_as_float(u[j] & 0xFFFF0000u);
            ax = fmaf(ee, hx, ax);
            ay = fmaf(ee, hy, ay);
            rowsum += ee;
        }
    }
    for (; idx < end; ++idx) {
        int2 p = pairs[idx];
        float ee = __int_as_float(p.y);
        unsigned u = hb[(size_t)p.x * 64 + lane];
        float hx = __uint_as_float(u << 16);
        float hy = __uint_as_float(u & 0xFFFF0000u);
        ax = fmaf(ee, hx, ax);
        ay = fmaf(ee, hy, ay);
        rowsum += ee;
    }
    float inv = 1.f / (rowsum + EPS);
    float x = ax * inv, y = ay * inv;
    x = x > 0.f ? x : (expf(x) - 1.f);
    y = y > 0.f ? y : (expf(y) - 1.f);
    float2 o = make_float2(x, y);
    *(float2*)&out[node * OUT_F + lane * 2] = o;
}

static inline size_t align_up(size_t v, size_t al) { return (v + al - 1) & ~(al - 1); }

extern "C" void kernel_launch(void* const* d_in, const int* in_sizes, int n_in,
                              void* d_out, int out_size, void* d_ws, size_t ws_size,
                              hipStream_t stream) {
    const float* input = (const float*)d_in[0];
    const int*   ei    = (const int*)d_in[1];
    const float* ew    = (const float*)d_in[2];
    const float* er    = (const float*)d_in[3];
    const float* W     = (const float*)d_in[4];
    const float* Wr    = (const float*)d_in[5];
    const float* a     = (const float*)d_in[6];
    float* out = (float*)d_out;

    const int n  = in_sizes[0] / IN_F;   // 50000
    const int nE = in_sizes[2];          // 1600000
    const int nbuck = (n + 127) >> 7;    // 391

    char* p = (char*)d_ws;
    size_t o = 0;
    unsigned short* hb = (unsigned short*)(p + o); o = align_up(o + (size_t)n * OUT_F * 2, 256);
    unsigned short* Wt = (unsigned short*)(p + o); o = align_up(o + (size_t)IN_F * OUT_F * 2, 256);
    float* hs      = (float*)(p + o); o = align_up(o + (size_t)n * 4, 256);
    float* hd      = (float*)(p + o); o = align_up(o + (size_t)n * 4, 256);
    int*   offs    = (int*)(p + o);   o = align_up(o + (size_t)(n + 1) * 4, 256);
    int2*  pairs   = (int2*)(p + o);  o = align_up(o + (size_t)nE * 8, 256);
    int2*  binned  = (int2*)(p + o);  o = align_up(o + (size_t)nE * 8, 256);
    int*   bcnt    = (int*)(p + o);   o = align_up(o + NBUCK_MAX * 4, 256);
    int*   boffB   = (int*)(p + o);   o = align_up(o + NBUCK_MAX * 4, 256);
    int*   bcursor = (int*)(p + o);   o = align_up(o + NBUCK_MAX * 4, 256);
    (void)ws_size; (void)n_in; (void)out_size;

    k_init<<<129, 256, 0, stream>>>(W, Wt, bcnt);
    k_gemm_hist<<<GEMM_BLOCKS + HIST_BLOCKS, 256, 0, stream>>>(input, Wt, a, hb, hs, hd,
                                                               ei, bcnt, nE, n);
    k_scanB<<<1, 256, 0, stream>>>(bcnt, boffB, bcursor, nbuck);
    int nchunk = (nE + CHUNK - 1) / CHUNK;
    k_edgebin<<<nchunk, 1024, 0, stream>>>(ei, ew, er, hs, hd, Wr, a,
                                           bcursor, binned, nE, n);
    k_sub<<<nbuck, 1024, 0, stream>>>(binned, bcnt, boffB, offs, pairs, n, nE);
    k_acc<<<(n + 3) / 4, 256, 0, stream>>>(pairs, offs, (const unsigned*)hb, out, n);
}